// Round 5
// baseline (430.267 us; speedup 1.0000x reference)
//
#include <hip/hip_runtime.h>

// Problem constants
#define B_SZ 512
#define C_CH 256
#define L_SEQ 256
#define H_DIM 512
#define T_STEP 16
#define W_WIN 8
#define NSLAB 24   // max distinct l values = T+W-1 = 23, round up

typedef __attribute__((ext_vector_type(8))) short short8;
typedef __attribute__((ext_vector_type(4))) float f32x4;

#define GLOBAL_U32 const __attribute__((address_space(1))) unsigned int*
#define LDS_U32 __attribute__((address_space(3))) unsigned int*
// async 16B/lane global->LDS; LDS dest = wave-uniform base + lane*16
#define ASYNC_COPY16(g, l) \
  __builtin_amdgcn_global_load_lds((GLOBAL_U32)(const void*)(g), (LDS_U32)(void*)(l), 16, 0, 0)

__device__ inline unsigned short f2bf(float x) {  // RNE f32 -> bf16
  unsigned u = __float_as_uint(x);
  u = (u + 0x7FFFu + ((u >> 16) & 1u)) >> 16;
  return (unsigned short)u;
}

// ---------------- cast f32 -> bf16 (4 elems/thread) ----------------
__global__ void cast_bf(const float* __restrict__ s, unsigned short* __restrict__ d, int n) {
  int i = (blockIdx.x * 256 + threadIdx.x) * 4;
  if (i < n) {
    float4 v = ((const float4*)s)[i >> 2];
    ushort4 o;
    o.x = f2bf(v.x); o.y = f2bf(v.y); o.z = f2bf(v.z); o.w = f2bf(v.w);
    ((ushort4*)d)[i >> 2] = o;
  }
}

// ---------------- encode slabs: F[l'][b][c] = bf16(features[b][c][lmin+l']) ----------------
// grid 512 (one block per b), 256 threads (one per c).
__global__ __launch_bounds__(256) void build_slabs2(const float* __restrict__ f,
                                                    unsigned short* __restrict__ F,
                                                    const int* __restrict__ tsp) {
  const int ts = tsp[0];
  const int lmin = min(ts + 1, L_SEQ - W_WIN);
  const int b = blockIdx.x;
  const int c = threadIdx.x;
  const float* src = f + ((size_t)b * C_CH + c) * L_SEQ;
  float v[NSLAB];
#pragma unroll
  for (int lp = 0; lp < NSLAB; lp++) {
    int l = lmin + lp;
    v[lp] = (l < L_SEQ) ? src[l] : 0.f;
  }
#pragma unroll
  for (int lp = 0; lp < NSLAB; lp++)
    F[((size_t)lp * B_SZ + b) * C_CH + c] = f2bf(v[lp]);
}

// ---------------- bf16 MFMA GEMM: D = A[M,K] * Bt[N,K]^T + bias[col] ----------------
template <int MODE>
__global__ __launch_bounds__(256) void gemm_bt(const unsigned short* __restrict__ A,
                                               const unsigned short* __restrict__ Bt,
                                               const float* __restrict__ bias,
                                               unsigned short* __restrict__ outb,
                                               float* __restrict__ outf, int K) {
  __shared__ __align__(16) unsigned short As[128 * 64];
  __shared__ __align__(16) unsigned short Bs[128 * 64];
  const int tid = threadIdx.x;
  const int wv = tid >> 6, lane = tid & 63, quad = lane >> 4, l15 = lane & 15;
  const int wm = wv >> 1, wn = wv & 1;
  const int M0 = blockIdx.x * 128, N0 = blockIdx.y * 128;

  f32x4 acc[4][4];
#pragma unroll
  for (int i = 0; i < 4; i++)
#pragma unroll
    for (int j = 0; j < 4; j++) acc[i][j] = (f32x4){0.f, 0.f, 0.f, 0.f};

  for (int k0 = 0; k0 < K; k0 += 64) {
#pragma unroll
    for (int i = 0; i < 4; i++) {
      int chunk = (i * 4 + wv) * 64 + lane;      // 1024 chunks of 16B = [128][64] bf16 tile
      int row = chunk >> 3, off = chunk & 7;     // 8 chunks per 128B row
      const unsigned short* ga = A + (size_t)(M0 + row) * K + k0 + off * 8;
      const unsigned short* gb = Bt + (size_t)(N0 + row) * K + k0 + off * 8;
      ASYNC_COPY16(ga, &As[(size_t)(i * 4 + wv) * 512]);
      ASYNC_COPY16(gb, &Bs[(size_t)(i * 4 + wv) * 512]);
    }
    __syncthreads();  // drains vmcnt
#pragma unroll
    for (int kk = 0; kk < 64; kk += 32) {
      short8 af[4], bfr[4];
#pragma unroll
      for (int i = 0; i < 4; i++)
        af[i] = *(const short8*)&As[(wm * 64 + i * 16 + l15) * 64 + kk + quad * 8];
#pragma unroll
      for (int j = 0; j < 4; j++)
        bfr[j] = *(const short8*)&Bs[(wn * 64 + j * 16 + l15) * 64 + kk + quad * 8];
#pragma unroll
      for (int i = 0; i < 4; i++)
#pragma unroll
        for (int j = 0; j < 4; j++)
          acc[i][j] = __builtin_amdgcn_mfma_f32_16x16x32_bf16(af[i], bfr[j], acc[i][j], 0, 0, 0);
    }
    __syncthreads();
  }

  // epilogue: D mapping col=lane&15, row=quad*4+reg (m89/m91-verified)
#pragma unroll
  for (int i = 0; i < 4; i++) {
    int rbase = M0 + wm * 64 + i * 16 + quad * 4;
#pragma unroll
    for (int j = 0; j < 4; j++) {
      int cc = N0 + wn * 64 + j * 16 + l15;
      float bv = bias[cc];
#pragma unroll
      for (int r = 0; r < 4; r++) {
        int rr = rbase + r;
        float v = acc[i][j][r] + bv;
        if (MODE == 0) {
          int t = cc >> 8, c = cc & 255, a = rr >> 3, w_ = rr & 7;
          outb[((size_t)(t * 8 + w_) * 512 + a) * 256 + c] = f2bf(v);
        } else {
          outf[(size_t)rr * 128 + cc] = v;
        }
      }
    }
  }
}

// ---------------- scores + fixed-shift logsumexp + diag, barrier-free streaming ----------------
// grid 1024 = bq(8) * 128 + tw  -> XCD = blockIdx%8 = tw%8: all 8 blocks sharing P[tw]
// land on the SAME XCD (L2 reuse). Block: 64 b-rows; wave: 16 rows. A-frags (E)
// register-resident (32 VGPRs); B-frags (P) streamed global->VGPR double-buffered
// (64 VGPRs); total ~115 VGPR -> no spill at 4 waves/EU.
#define NCE_SHIFT 40.0f
__global__ __launch_bounds__(256, 4) void scores_nce3(const unsigned short* __restrict__ F,
                                                      const unsigned short* __restrict__ pred,
                                                      const int* __restrict__ tsp,
                                                      float* __restrict__ partials) {
  const int tid = threadIdx.x;
  const int wv = tid >> 6, lane = tid & 63, quad = lane >> 4, l15 = lane & 15;
  const int blk = blockIdx.x;
  const int bq = blk >> 7;    // 0..7
  const int tw = blk & 127;   // 0..127
  const int t = tw >> 3, w_ = tw & 7;
  const int ts = tsp[0];
  const int lmin = min(ts + 1, L_SEQ - W_WIN);
  const int lp = min(ts + 1 + t, L_SEQ - W_WIN) + w_ - lmin;
  const unsigned short* E = F + (size_t)lp * (B_SZ * C_CH);
  const unsigned short* P = pred + (size_t)tw * (B_SZ * C_CH);

  const int rowb = bq * 64 + wv * 16;

  // A-fragments: af[kk] = E[rowb + l15][kk*32 + quad*8 ..+8]  (16 rows, K=256 resident)
  short8 af[8];
#pragma unroll
  for (int kk = 0; kk < 8; kk++)
    af[kk] = *(const short8*)(E + (size_t)(rowb + l15) * C_CH + kk * 32 + quad * 8);

  float sumr[4] = {0.f, 0.f, 0.f, 0.f};
  float dg[4] = {0.f, 0.f, 0.f, 0.f};
  const int chd = bq * 4 + wv;  // a-chunk containing this wave's diagonal (wave-uniform)

  short8 bf[2][8];
#pragma unroll
  for (int kk = 0; kk < 8; kk++)
    bf[0][kk] = *(const short8*)(P + (size_t)l15 * C_CH + kk * 32 + quad * 8);

#pragma unroll
  for (int ch = 0; ch < 32; ch++) {
    const int cur = ch & 1, nxt = cur ^ 1;
    if (ch < 31) {
#pragma unroll
      for (int kk = 0; kk < 8; kk++)
        bf[nxt][kk] =
            *(const short8*)(P + (size_t)((ch + 1) * 16 + l15) * C_CH + kk * 32 + quad * 8);
    }
    f32x4 acc = (f32x4){0.f, 0.f, 0.f, 0.f};
#pragma unroll
    for (int kk = 0; kk < 8; kk++)
      acc = __builtin_amdgcn_mfma_f32_16x16x32_bf16(af[kk], bf[cur][kk], acc, 0, 0, 0);
    if (ch == chd) {  // wave-uniform branch
#pragma unroll
      for (int r = 0; r < 4; r++)
        if (l15 == quad * 4 + r) dg[r] = acc[r];
    }
#pragma unroll
    for (int r = 0; r < 4; r++) sumr[r] += __expf(acc[r] - NCE_SHIFT);
  }

  // per-row logsumexp + diag -> lane partial
  float lane_nce = 0.f;
#pragma unroll
  for (int r = 0; r < 4; r++) {
    float s = sumr[r];
    s += __shfl_xor(s, 1);
    s += __shfl_xor(s, 2);
    s += __shfl_xor(s, 4);
    s += __shfl_xor(s, 8);
    if (l15 == quad * 4 + r) lane_nce += __logf(s) + NCE_SHIFT - dg[r];
  }
  for (int d = 1; d < 64; d <<= 1) lane_nce += __shfl_xor(lane_nce, d);

  __shared__ float wsum[4];
  if (lane == 0) wsum[wv] = lane_nce;
  __syncthreads();
  if (tid == 0) partials[blk] = wsum[0] + wsum[1] + wsum[2] + wsum[3];
}

__global__ void nce_finish(const float* __restrict__ partials, float* __restrict__ out) {
  __shared__ float r[256];
  float s = 0.f;
  for (int i = threadIdx.x; i < 1024; i += 256) s += partials[i];
  r[threadIdx.x] = s;
  __syncthreads();
  if (threadIdx.x == 0) {
    float tsum = 0.f;
    for (int i = 0; i < 256; i++) tsum += r[i];
    // partials hold sum(lse - diag) = sum(-logp_diag); nce = +sum/N
    out[0] = tsum / 65536.0f;  // B*T*W
  }
}

// ---------------- BN train stats (two stage, fp32) ----------------
__global__ void bn_stage1(const float* __restrict__ h1, float* __restrict__ p1,
                          float* __restrict__ p2) {
  int c = threadIdx.x;  // 128 threads
  int blk = blockIdx.x; // 32 blocks x 128 rows
  float s1 = 0.f, s2 = 0.f;
  for (int r = blk * 128; r < blk * 128 + 128; r++) {
    float v = h1[(size_t)r * 128 + c];
    s1 += v;
    s2 += v * v;
  }
  p1[blk * 128 + c] = s1;
  p2[blk * 128 + c] = s2;
}

__global__ void bn_stage2(const float* __restrict__ p1, const float* __restrict__ p2,
                          const float* __restrict__ g, const float* __restrict__ b,
                          float* __restrict__ sc, float* __restrict__ sh) {
  int c = threadIdx.x;
  float s1 = 0.f, s2 = 0.f;
  for (int k = 0; k < 32; k++) {
    s1 += p1[k * 128 + c];
    s2 += p2[k * 128 + c];
  }
  float mean = s1 * (1.f / 4096.f);
  float var = s2 * (1.f / 4096.f) - mean * mean;  // biased (BN train)
  float scale = g[c] * rsqrtf(var + 1e-5f);
  sc[c] = scale;
  sh[c] = b[c] - mean * scale;
}

// ---------------- BN-apply + ReLU + GEMM2 -> proj (fp32) ----------------
__global__ __launch_bounds__(256) void proj_gemm2(const float* __restrict__ h1,
                                                  const float* __restrict__ sc,
                                                  const float* __restrict__ sh,
                                                  const float* __restrict__ pw2,
                                                  const float* __restrict__ pb2,
                                                  float* __restrict__ out) {
  __shared__ float pw2s[64][129];  // +1 pad breaks bank aliasing
  __shared__ float hs[16][129];
  __shared__ float scs[128], shs[128];
  int tid = threadIdx.x;
  for (int idx = tid; idx < 64 * 128; idx += 256) pw2s[idx >> 7][idx & 127] = pw2[idx];
  if (tid < 128) { scs[tid] = sc[tid]; shs[tid] = sh[tid]; }
  __syncthreads();
  int r0 = blockIdx.x * 64;
  float bb = pb2[tid & 63];
  for (int ch = 0; ch < 4; ch++) {
    int rr0 = r0 + ch * 16;
    for (int idx = tid; idx < 16 * 128; idx += 256) {
      int r = idx >> 7, c = idx & 127;
      float v = h1[(size_t)(rr0 + r) * 128 + c];
      hs[r][c] = fmaxf(v * scs[c] + shs[c], 0.f);
    }
    __syncthreads();
    int oc = tid & 63, og = tid >> 6;
#pragma unroll
    for (int q = 0; q < 4; q++) {
      int row = og * 4 + q;
      float s = bb;
      for (int c = 0; c < 128; c++) s += hs[row][c] * pw2s[oc][c];
      out[(size_t)(rr0 + row) * 64 + oc] = s;
    }
    __syncthreads();
  }
}

extern "C" void kernel_launch(void* const* d_in, const int* in_sizes, int n_in,
                              void* d_out, int out_size, void* d_ws, size_t ws_size,
                              hipStream_t stream) {
  const float* features = (const float*)d_in[0];
  const float* c_t      = (const float*)d_in[1];
  const float* Wk_w     = (const float*)d_in[2];
  const float* Wk_b     = (const float*)d_in[3];
  const float* pw1      = (const float*)d_in[4];
  const float* pb1      = (const float*)d_in[5];
  const float* bn_gamma = (const float*)d_in[6];
  const float* bn_beta  = (const float*)d_in[7];
  const float* pw2      = (const float*)d_in[8];
  const float* pb2      = (const float*)d_in[9];
  const int*   tsp      = (const int*)d_in[10];
  float* out = (float*)d_out;

  // workspace carve-up (~48.2 MB total)
  char* ws = (char*)d_ws;
  size_t off = 0;
  auto carve = [&](size_t bytes) { void* p = ws + off; off += (bytes + 255) & ~(size_t)255; return p; };
  unsigned short* ct_bf  = (unsigned short*)carve((size_t)4096 * 512 * 2);   // c_t bf16 [bw][h]
  unsigned short* wk_bf  = (unsigned short*)carve((size_t)4096 * 512 * 2);   // Wk bf16 [tc][h]
  unsigned short* pw1_bf = (unsigned short*)carve((size_t)128 * 512 * 2);
  unsigned short* F      = (unsigned short*)carve((size_t)NSLAB * 512 * 256 * 2);
  unsigned short* pred   = (unsigned short*)carve((size_t)16 * 8 * 512 * 256 * 2);
  float* h1    = (float*)carve((size_t)4096 * 128 * 4);
  float* bnp1  = (float*)carve((size_t)32 * 128 * 4);
  float* bnp2  = (float*)carve((size_t)32 * 128 * 4);
  float* bnsc  = (float*)carve((size_t)128 * 4);
  float* bnsh  = (float*)carve((size_t)128 * 4);
  float* parts = (float*)carve((size_t)2048 * 4);

  cast_bf<<<2048, 256, 0, stream>>>(c_t, ct_bf, 4096 * 512);
  cast_bf<<<2048, 256, 0, stream>>>(Wk_w, wk_bf, 4096 * 512);
  cast_bf<<<64, 256, 0, stream>>>(pw1, pw1_bf, 128 * 512);
  build_slabs2<<<512, 256, 0, stream>>>(features, F, tsp);

  // pred[t][w][a][c] = c_t @ Wk^T + Wk_b   (M=N=4096, K=512)
  gemm_bt<0><<<dim3(32, 32), 256, 0, stream>>>(ct_bf, wk_bf, Wk_b, pred, nullptr, 512);
  // h1 = c_t2d @ pw1^T + pb1   (M=4096, N=128, K=512)
  gemm_bt<1><<<dim3(32, 1), 256, 0, stream>>>(ct_bf, pw1_bf, pb1, nullptr, h1, 512);

  scores_nce3<<<1024, 256, 0, stream>>>(F, pred, tsp, parts);
  nce_finish<<<1, 256, 0, stream>>>(parts, out);

  bn_stage1<<<32, 128, 0, stream>>>(h1, bnp1, bnp2);
  bn_stage2<<<1, 128, 0, stream>>>(bnp1, bnp2, bn_gamma, bn_beta, bnsc, bnsh);
  proj_gemm2<<<64, 256, 0, stream>>>(h1, bnsc, bnsh, pw2, pb2, out + 1);
}

// Round 6
// 412.292 us; speedup vs baseline: 1.0436x; 1.0436x over previous
//
#include <hip/hip_runtime.h>

// Problem constants
#define B_SZ 512
#define C_CH 256
#define L_SEQ 256
#define H_DIM 512
#define T_STEP 16
#define W_WIN 8
#define NSLAB 24   // max distinct l values = T+W-1 = 23, round up

typedef __attribute__((ext_vector_type(8))) short short8;
typedef __attribute__((ext_vector_type(4))) float f32x4;

#define GLOBAL_U32 const __attribute__((address_space(1))) unsigned int*
#define LDS_U32 __attribute__((address_space(3))) unsigned int*
// async 16B/lane global->LDS; LDS dest = wave-uniform base + lane*16
#define ASYNC_COPY16(g, l) \
  __builtin_amdgcn_global_load_lds((GLOBAL_U32)(const void*)(g), (LDS_U32)(void*)(l), 16, 0, 0)

__device__ inline unsigned short f2bf(float x) {  // RNE f32 -> bf16
  unsigned u = __float_as_uint(x);
  u = (u + 0x7FFFu + ((u >> 16) & 1u)) >> 16;
  return (unsigned short)u;
}

// ---------------- cast f32 -> bf16 (4 elems/thread) ----------------
__global__ void cast_bf(const float* __restrict__ s, unsigned short* __restrict__ d, int n) {
  int i = (blockIdx.x * 256 + threadIdx.x) * 4;
  if (i < n) {
    float4 v = ((const float4*)s)[i >> 2];
    ushort4 o;
    o.x = f2bf(v.x); o.y = f2bf(v.y); o.z = f2bf(v.z); o.w = f2bf(v.w);
    ((ushort4*)d)[i >> 2] = o;
  }
}

// ---------------- encode slabs: F[l'][b][c] = bf16(features[b][c][lmin+l']) ----------------
// grid 512 (one block per b), 256 threads (one per c).
__global__ __launch_bounds__(256) void build_slabs2(const float* __restrict__ f,
                                                    unsigned short* __restrict__ F,
                                                    const int* __restrict__ tsp) {
  const int ts = tsp[0];
  const int lmin = min(ts + 1, L_SEQ - W_WIN);
  const int b = blockIdx.x;
  const int c = threadIdx.x;
  const float* src = f + ((size_t)b * C_CH + c) * L_SEQ;
  float v[NSLAB];
#pragma unroll
  for (int lp = 0; lp < NSLAB; lp++) {
    int l = lmin + lp;
    v[lp] = (l < L_SEQ) ? src[l] : 0.f;
  }
#pragma unroll
  for (int lp = 0; lp < NSLAB; lp++)
    F[((size_t)lp * B_SZ + b) * C_CH + c] = f2bf(v[lp]);
}

// ---------------- bf16 MFMA GEMM: D = A[M,K] * Bt[N,K]^T + bias[col] ----------------
template <int MODE>
__global__ __launch_bounds__(256) void gemm_bt(const unsigned short* __restrict__ A,
                                               const unsigned short* __restrict__ Bt,
                                               const float* __restrict__ bias,
                                               unsigned short* __restrict__ outb,
                                               float* __restrict__ outf, int K) {
  __shared__ __align__(16) unsigned short As[128 * 64];
  __shared__ __align__(16) unsigned short Bs[128 * 64];
  const int tid = threadIdx.x;
  const int wv = tid >> 6, lane = tid & 63, quad = lane >> 4, l15 = lane & 15;
  const int wm = wv >> 1, wn = wv & 1;
  const int M0 = blockIdx.x * 128, N0 = blockIdx.y * 128;

  f32x4 acc[4][4];
#pragma unroll
  for (int i = 0; i < 4; i++)
#pragma unroll
    for (int j = 0; j < 4; j++) acc[i][j] = (f32x4){0.f, 0.f, 0.f, 0.f};

  for (int k0 = 0; k0 < K; k0 += 64) {
#pragma unroll
    for (int i = 0; i < 4; i++) {
      int chunk = (i * 4 + wv) * 64 + lane;      // 1024 chunks of 16B = [128][64] bf16 tile
      int row = chunk >> 3, off = chunk & 7;     // 8 chunks per 128B row
      const unsigned short* ga = A + (size_t)(M0 + row) * K + k0 + off * 8;
      const unsigned short* gb = Bt + (size_t)(N0 + row) * K + k0 + off * 8;
      ASYNC_COPY16(ga, &As[(size_t)(i * 4 + wv) * 512]);
      ASYNC_COPY16(gb, &Bs[(size_t)(i * 4 + wv) * 512]);
    }
    __syncthreads();  // drains vmcnt
#pragma unroll
    for (int kk = 0; kk < 64; kk += 32) {
      short8 af[4], bfr[4];
#pragma unroll
      for (int i = 0; i < 4; i++)
        af[i] = *(const short8*)&As[(wm * 64 + i * 16 + l15) * 64 + kk + quad * 8];
#pragma unroll
      for (int j = 0; j < 4; j++)
        bfr[j] = *(const short8*)&Bs[(wn * 64 + j * 16 + l15) * 64 + kk + quad * 8];
#pragma unroll
      for (int i = 0; i < 4; i++)
#pragma unroll
        for (int j = 0; j < 4; j++)
          acc[i][j] = __builtin_amdgcn_mfma_f32_16x16x32_bf16(af[i], bfr[j], acc[i][j], 0, 0, 0);
    }
    __syncthreads();
  }

  // epilogue: D mapping col=lane&15, row=quad*4+reg (m89/m91-verified)
#pragma unroll
  for (int i = 0; i < 4; i++) {
    int rbase = M0 + wm * 64 + i * 16 + quad * 4;
#pragma unroll
    for (int j = 0; j < 4; j++) {
      int cc = N0 + wn * 64 + j * 16 + l15;
      float bv = bias[cc];
#pragma unroll
      for (int r = 0; r < 4; r++) {
        int rr = rbase + r;
        float v = acc[i][j][r] + bv;
        if (MODE == 0) {
          int t = cc >> 8, c = cc & 255, a = rr >> 3, w_ = rr & 7;
          outb[((size_t)(t * 8 + w_) * 512 + a) * 256 + c] = f2bf(v);
        } else {
          outf[(size_t)rr * 128 + cc] = v;
        }
      }
    }
  }
}

// ---------------- scores + fixed-shift logsumexp + diag, barrier-free streaming ----------------
// grid 1024 = bq(8)*128 + tw -> XCD = blk%8 = tw%8: blocks sharing P[tw] on the same XCD.
// Wave: 16 E-rows, all 512 P-cols. af[8] register-resident; bf[8] SINGLE-buffered
// (demand ~90 VGPR -> no spill; latency hidden by 4 waves/SIMD co-schedule, m114).
#define NCE_SHIFT 40.0f
__global__ __launch_bounds__(256) void scores_nce4(const unsigned short* __restrict__ F,
                                                   const unsigned short* __restrict__ pred,
                                                   const int* __restrict__ tsp,
                                                   float* __restrict__ partials) {
  const int tid = threadIdx.x;
  const int wv = tid >> 6, lane = tid & 63, quad = lane >> 4, l15 = lane & 15;
  const int blk = blockIdx.x;
  const int bq = blk >> 7;    // 0..7
  const int tw = blk & 127;   // 0..127
  const int t = tw >> 3, w_ = tw & 7;
  const int ts = tsp[0];
  const int lmin = min(ts + 1, L_SEQ - W_WIN);
  const int lp = min(ts + 1 + t, L_SEQ - W_WIN) + w_ - lmin;
  const unsigned short* E = F + (size_t)lp * (B_SZ * C_CH);
  const unsigned short* P = pred + (size_t)tw * (B_SZ * C_CH);

  const int rowb = bq * 64 + wv * 16;

  // A-fragments: af[kk] = E[rowb + l15][kk*32 + quad*8 ..+8]  (16 rows, K=256 resident)
  short8 af[8];
#pragma unroll
  for (int kk = 0; kk < 8; kk++)
    af[kk] = *(const short8*)(E + (size_t)(rowb + l15) * C_CH + kk * 32 + quad * 8);

  float sumr[4] = {0.f, 0.f, 0.f, 0.f};
  float dg[4] = {0.f, 0.f, 0.f, 0.f};
  const int chd = bq * 4 + wv;  // a-chunk containing this wave's diagonal (wave-uniform)

#pragma unroll
  for (int ch = 0; ch < 32; ch++) {
    short8 bf[8];
#pragma unroll
    for (int kk = 0; kk < 8; kk++)
      bf[kk] = *(const short8*)(P + (size_t)(ch * 16 + l15) * C_CH + kk * 32 + quad * 8);
    f32x4 acc = (f32x4){0.f, 0.f, 0.f, 0.f};
#pragma unroll
    for (int kk = 0; kk < 8; kk++)
      acc = __builtin_amdgcn_mfma_f32_16x16x32_bf16(af[kk], bf[kk], acc, 0, 0, 0);
    if (ch == chd) {  // wave-uniform branch
#pragma unroll
      for (int r = 0; r < 4; r++)
        if (l15 == quad * 4 + r) dg[r] = acc[r];
    }
#pragma unroll
    for (int r = 0; r < 4; r++) sumr[r] += __expf(acc[r] - NCE_SHIFT);
  }

  // per-row logsumexp + diag -> lane partial
  float lane_nce = 0.f;
#pragma unroll
  for (int r = 0; r < 4; r++) {
    float s = sumr[r];
    s += __shfl_xor(s, 1);
    s += __shfl_xor(s, 2);
    s += __shfl_xor(s, 4);
    s += __shfl_xor(s, 8);
    if (l15 == quad * 4 + r) lane_nce += __logf(s) + NCE_SHIFT - dg[r];
  }
  for (int d = 1; d < 64; d <<= 1) lane_nce += __shfl_xor(lane_nce, d);

  __shared__ float wsum[4];
  if (lane == 0) wsum[wv] = lane_nce;
  __syncthreads();
  if (tid == 0) partials[blk] = wsum[0] + wsum[1] + wsum[2] + wsum[3];
}

__global__ void nce_finish(const float* __restrict__ partials, float* __restrict__ out) {
  __shared__ float r[256];
  float s = 0.f;
  for (int i = threadIdx.x; i < 1024; i += 256) s += partials[i];
  r[threadIdx.x] = s;
  __syncthreads();
  if (threadIdx.x == 0) {
    float tsum = 0.f;
    for (int i = 0; i < 256; i++) tsum += r[i];
    // partials hold sum(lse - diag) = sum(-logp_diag); nce = +sum/N
    out[0] = tsum / 65536.0f;  // B*T*W
  }
}

// ---------------- BN train stats (two stage, fp32) ----------------
__global__ void bn_stage1(const float* __restrict__ h1, float* __restrict__ p1,
                          float* __restrict__ p2) {
  int c = threadIdx.x;  // 128 threads
  int blk = blockIdx.x; // 32 blocks x 128 rows
  float s1 = 0.f, s2 = 0.f;
  for (int r = blk * 128; r < blk * 128 + 128; r++) {
    float v = h1[(size_t)r * 128 + c];
    s1 += v;
    s2 += v * v;
  }
  p1[blk * 128 + c] = s1;
  p2[blk * 128 + c] = s2;
}

__global__ void bn_stage2(const float* __restrict__ p1, const float* __restrict__ p2,
                          const float* __restrict__ g, const float* __restrict__ b,
                          float* __restrict__ sc, float* __restrict__ sh) {
  int c = threadIdx.x;
  float s1 = 0.f, s2 = 0.f;
  for (int k = 0; k < 32; k++) {
    s1 += p1[k * 128 + c];
    s2 += p2[k * 128 + c];
  }
  float mean = s1 * (1.f / 4096.f);
  float var = s2 * (1.f / 4096.f) - mean * mean;  // biased (BN train)
  float scale = g[c] * rsqrtf(var + 1e-5f);
  sc[c] = scale;
  sh[c] = b[c] - mean * scale;
}

// ---------------- BN-apply + ReLU + GEMM2 -> proj (fp32) ----------------
__global__ __launch_bounds__(256) void proj_gemm2(const float* __restrict__ h1,
                                                  const float* __restrict__ sc,
                                                  const float* __restrict__ sh,
                                                  const float* __restrict__ pw2,
                                                  const float* __restrict__ pb2,
                                                  float* __restrict__ out) {
  __shared__ float pw2s[64][129];  // +1 pad breaks bank aliasing
  __shared__ float hs[16][129];
  __shared__ float scs[128], shs[128];
  int tid = threadIdx.x;
  for (int idx = tid; idx < 64 * 128; idx += 256) pw2s[idx >> 7][idx & 127] = pw2[idx];
  if (tid < 128) { scs[tid] = sc[tid]; shs[tid] = sh[tid]; }
  __syncthreads();
  int r0 = blockIdx.x * 64;
  float bb = pb2[tid & 63];
  for (int ch = 0; ch < 4; ch++) {
    int rr0 = r0 + ch * 16;
    for (int idx = tid; idx < 16 * 128; idx += 256) {
      int r = idx >> 7, c = idx & 127;
      float v = h1[(size_t)(rr0 + r) * 128 + c];
      hs[r][c] = fmaxf(v * scs[c] + shs[c], 0.f);
    }
    __syncthreads();
    int oc = tid & 63, og = tid >> 6;
#pragma unroll
    for (int q = 0; q < 4; q++) {
      int row = og * 4 + q;
      float s = bb;
      for (int c = 0; c < 128; c++) s += hs[row][c] * pw2s[oc][c];
      out[(size_t)(rr0 + row) * 64 + oc] = s;
    }
    __syncthreads();
  }
}

extern "C" void kernel_launch(void* const* d_in, const int* in_sizes, int n_in,
                              void* d_out, int out_size, void* d_ws, size_t ws_size,
                              hipStream_t stream) {
  const float* features = (const float*)d_in[0];
  const float* c_t      = (const float*)d_in[1];
  const float* Wk_w     = (const float*)d_in[2];
  const float* Wk_b     = (const float*)d_in[3];
  const float* pw1      = (const float*)d_in[4];
  const float* pb1      = (const float*)d_in[5];
  const float* bn_gamma = (const float*)d_in[6];
  const float* bn_beta  = (const float*)d_in[7];
  const float* pw2      = (const float*)d_in[8];
  const float* pb2      = (const float*)d_in[9];
  const int*   tsp      = (const int*)d_in[10];
  float* out = (float*)d_out;

  // workspace carve-up (~48.2 MB total)
  char* ws = (char*)d_ws;
  size_t off = 0;
  auto carve = [&](size_t bytes) { void* p = ws + off; off += (bytes + 255) & ~(size_t)255; return p; };
  unsigned short* ct_bf  = (unsigned short*)carve((size_t)4096 * 512 * 2);   // c_t bf16 [bw][h]
  unsigned short* wk_bf  = (unsigned short*)carve((size_t)4096 * 512 * 2);   // Wk bf16 [tc][h]
  unsigned short* pw1_bf = (unsigned short*)carve((size_t)128 * 512 * 2);
  unsigned short* F      = (unsigned short*)carve((size_t)NSLAB * 512 * 256 * 2);
  unsigned short* pred   = (unsigned short*)carve((size_t)16 * 8 * 512 * 256 * 2);
  float* h1    = (float*)carve((size_t)4096 * 128 * 4);
  float* bnp1  = (float*)carve((size_t)32 * 128 * 4);
  float* bnp2  = (float*)carve((size_t)32 * 128 * 4);
  float* bnsc  = (float*)carve((size_t)128 * 4);
  float* bnsh  = (float*)carve((size_t)128 * 4);
  float* parts = (float*)carve((size_t)2048 * 4);

  cast_bf<<<2048, 256, 0, stream>>>(c_t, ct_bf, 4096 * 512);
  cast_bf<<<2048, 256, 0, stream>>>(Wk_w, wk_bf, 4096 * 512);
  cast_bf<<<64, 256, 0, stream>>>(pw1, pw1_bf, 128 * 512);
  build_slabs2<<<512, 256, 0, stream>>>(features, F, tsp);

  // pred[t][w][a][c] = c_t @ Wk^T + Wk_b   (M=N=4096, K=512)
  gemm_bt<0><<<dim3(32, 32), 256, 0, stream>>>(ct_bf, wk_bf, Wk_b, pred, nullptr, 512);
  // h1 = c_t2d @ pw1^T + pb1   (M=4096, N=128, K=512)
  gemm_bt<1><<<dim3(32, 1), 256, 0, stream>>>(ct_bf, pw1_bf, pb1, nullptr, h1, 512);

  scores_nce4<<<1024, 256, 0, stream>>>(F, pred, tsp, parts);
  nce_finish<<<1, 256, 0, stream>>>(parts, out);

  bn_stage1<<<32, 128, 0, stream>>>(h1, bnp1, bnp2);
  bn_stage2<<<1, 128, 0, stream>>>(bnp1, bnp2, bn_gamma, bn_beta, bnsc, bnsh);
  proj_gemm2<<<64, 256, 0, stream>>>(h1, bnsc, bnsh, pw2, pb2, out + 1);
}

// Round 7
// 331.070 us; speedup vs baseline: 1.2996x; 1.2453x over previous
//
#include <hip/hip_runtime.h>

// Problem constants
#define B_SZ 512
#define C_CH 256
#define L_SEQ 256
#define H_DIM 512
#define T_STEP 16
#define W_WIN 8
#define NSLAB 24   // max distinct l values = T+W-1 = 23, round up
#define NCE_SHIFT 40.0f

typedef __attribute__((ext_vector_type(8))) short short8;
typedef __attribute__((ext_vector_type(4))) float f32x4;

#define GLOBAL_U32 const __attribute__((address_space(1))) unsigned int*
#define LDS_U32 __attribute__((address_space(3))) unsigned int*
// async 16B/lane global->LDS; LDS dest = wave-uniform base + lane*16
#define ASYNC_COPY16(g, l) \
  __builtin_amdgcn_global_load_lds((GLOBAL_U32)(const void*)(g), (LDS_U32)(void*)(l), 16, 0, 0)

__device__ inline unsigned short f2bf(float x) {  // RNE f32 -> bf16
  unsigned u = __float_as_uint(x);
  u = (u + 0x7FFFu + ((u >> 16) & 1u)) >> 16;
  return (unsigned short)u;
}

// ---------------- cast f32 -> bf16 (4 elems/thread) ----------------
__global__ void cast_bf(const float* __restrict__ s, unsigned short* __restrict__ d, int n) {
  int i = (blockIdx.x * 256 + threadIdx.x) * 4;
  if (i < n) {
    float4 v = ((const float4*)s)[i >> 2];
    ushort4 o;
    o.x = f2bf(v.x); o.y = f2bf(v.y); o.z = f2bf(v.z); o.w = f2bf(v.w);
    ((ushort4*)d)[i >> 2] = o;
  }
}

// ---------------- encode slabs: F[l'][b][c] = bf16(features[b][c][lmin+l']) ----------------
// grid 512 (one block per b), 256 threads (one per c).
__global__ __launch_bounds__(256) void build_slabs2(const float* __restrict__ f,
                                                    unsigned short* __restrict__ F,
                                                    const int* __restrict__ tsp) {
  const int ts = tsp[0];
  const int lmin = min(ts + 1, L_SEQ - W_WIN);
  const int b = blockIdx.x;
  const int c = threadIdx.x;
  const float* src = f + ((size_t)b * C_CH + c) * L_SEQ;
  float v[NSLAB];
#pragma unroll
  for (int lp = 0; lp < NSLAB; lp++) {
    int l = lmin + lp;
    v[lp] = (l < L_SEQ) ? src[l] : 0.f;
  }
#pragma unroll
  for (int lp = 0; lp < NSLAB; lp++)
    F[((size_t)lp * B_SZ + b) * C_CH + c] = f2bf(v[lp]);
}

// ---------------- bf16 MFMA GEMM: D = A[M,K] * Bt[N,K]^T + bias[col] ----------------
template <int MODE>
__global__ __launch_bounds__(256) void gemm_bt(const unsigned short* __restrict__ A,
                                               const unsigned short* __restrict__ Bt,
                                               const float* __restrict__ bias,
                                               unsigned short* __restrict__ outb,
                                               float* __restrict__ outf, int K) {
  __shared__ __align__(16) unsigned short As[128 * 64];
  __shared__ __align__(16) unsigned short Bs[128 * 64];
  const int tid = threadIdx.x;
  const int wv = tid >> 6, lane = tid & 63, quad = lane >> 4, l15 = lane & 15;
  const int wm = wv >> 1, wn = wv & 1;
  const int M0 = blockIdx.x * 128, N0 = blockIdx.y * 128;

  f32x4 acc[4][4];
#pragma unroll
  for (int i = 0; i < 4; i++)
#pragma unroll
    for (int j = 0; j < 4; j++) acc[i][j] = (f32x4){0.f, 0.f, 0.f, 0.f};

  for (int k0 = 0; k0 < K; k0 += 64) {
#pragma unroll
    for (int i = 0; i < 4; i++) {
      int chunk = (i * 4 + wv) * 64 + lane;      // 1024 chunks of 16B = [128][64] bf16 tile
      int row = chunk >> 3, off = chunk & 7;     // 8 chunks per 128B row
      const unsigned short* ga = A + (size_t)(M0 + row) * K + k0 + off * 8;
      const unsigned short* gb = Bt + (size_t)(N0 + row) * K + k0 + off * 8;
      ASYNC_COPY16(ga, &As[(size_t)(i * 4 + wv) * 512]);
      ASYNC_COPY16(gb, &Bs[(size_t)(i * 4 + wv) * 512]);
    }
    __syncthreads();  // drains vmcnt
#pragma unroll
    for (int kk = 0; kk < 64; kk += 32) {
      short8 af[4], bfr[4];
#pragma unroll
      for (int i = 0; i < 4; i++)
        af[i] = *(const short8*)&As[(wm * 64 + i * 16 + l15) * 64 + kk + quad * 8];
#pragma unroll
      for (int j = 0; j < 4; j++)
        bfr[j] = *(const short8*)&Bs[(wn * 64 + j * 16 + l15) * 64 + kk + quad * 8];
#pragma unroll
      for (int i = 0; i < 4; i++)
#pragma unroll
        for (int j = 0; j < 4; j++)
          acc[i][j] = __builtin_amdgcn_mfma_f32_16x16x32_bf16(af[i], bfr[j], acc[i][j], 0, 0, 0);
    }
    __syncthreads();
  }

  // epilogue: D mapping col=lane&15, row=quad*4+reg (m89/m91-verified)
#pragma unroll
  for (int i = 0; i < 4; i++) {
    int rbase = M0 + wm * 64 + i * 16 + quad * 4;
#pragma unroll
    for (int j = 0; j < 4; j++) {
      int cc = N0 + wn * 64 + j * 16 + l15;
      float bv = bias[cc];
#pragma unroll
      for (int r = 0; r < 4; r++) {
        int rr = rbase + r;
        float v = acc[i][j][r] + bv;
        if (MODE == 0) {
          int t = cc >> 8, c = cc & 255, a = rr >> 3, w_ = rr & 7;
          outb[((size_t)(t * 8 + w_) * 512 + a) * 256 + c] = f2bf(v);
        } else {
          outf[(size_t)rr * 128 + cc] = v;
        }
      }
    }
  }
}

// ---------------- scores GEMM tile + exp-sum/diag epilogue ----------------
// grid (4 rowblk, 4 colblk, 128 tw): per tw, scores[b][a] = E[b]·P[a], 512x512, K=256.
// Same staged-LDS MFMA body as gemm_bt (m97 structure). Epilogue: per-row
// sum of exp(s-SHIFT) reduced in-wave, one atomicAdd per row-half into
// rowsum[tw][b]; diagonal blocks write diagv[tw][b] directly.
__global__ __launch_bounds__(256) void scores_gemm(const unsigned short* __restrict__ F,
                                                   const unsigned short* __restrict__ pred,
                                                   const int* __restrict__ tsp,
                                                   float* __restrict__ rowsum,
                                                   float* __restrict__ diagv) {
  __shared__ __align__(16) unsigned short As[128 * 64];
  __shared__ __align__(16) unsigned short Bs[128 * 64];
  const int tid = threadIdx.x;
  const int wv = tid >> 6, lane = tid & 63, quad = lane >> 4, l15 = lane & 15;
  const int wm = wv >> 1, wn = wv & 1;
  const int rowblk = blockIdx.x, colblk = blockIdx.y, tw = blockIdx.z;
  const int t = tw >> 3, w_ = tw & 7;
  const int ts = tsp[0];
  const int lmin = min(ts + 1, L_SEQ - W_WIN);
  const int lp = min(ts + 1 + t, L_SEQ - W_WIN) + w_ - lmin;
  const unsigned short* A = F + (size_t)lp * (B_SZ * C_CH) + (size_t)rowblk * 128 * C_CH;
  const unsigned short* Bt = pred + (size_t)tw * (B_SZ * C_CH) + (size_t)colblk * 128 * C_CH;

  f32x4 acc[4][4];
#pragma unroll
  for (int i = 0; i < 4; i++)
#pragma unroll
    for (int j = 0; j < 4; j++) acc[i][j] = (f32x4){0.f, 0.f, 0.f, 0.f};

  for (int k0 = 0; k0 < C_CH; k0 += 64) {
#pragma unroll
    for (int i = 0; i < 4; i++) {
      int chunk = (i * 4 + wv) * 64 + lane;
      int row = chunk >> 3, off = chunk & 7;
      ASYNC_COPY16(A + (size_t)row * C_CH + k0 + off * 8, &As[(size_t)(i * 4 + wv) * 512]);
      ASYNC_COPY16(Bt + (size_t)row * C_CH + k0 + off * 8, &Bs[(size_t)(i * 4 + wv) * 512]);
    }
    __syncthreads();
#pragma unroll
    for (int kk = 0; kk < 64; kk += 32) {
      short8 af[4], bfr[4];
#pragma unroll
      for (int i = 0; i < 4; i++)
        af[i] = *(const short8*)&As[(wm * 64 + i * 16 + l15) * 64 + kk + quad * 8];
#pragma unroll
      for (int j = 0; j < 4; j++)
        bfr[j] = *(const short8*)&Bs[(wn * 64 + j * 16 + l15) * 64 + kk + quad * 8];
#pragma unroll
      for (int i = 0; i < 4; i++)
#pragma unroll
        for (int j = 0; j < 4; j++)
          acc[i][j] = __builtin_amdgcn_mfma_f32_16x16x32_bf16(af[i], bfr[j], acc[i][j], 0, 0, 0);
    }
    __syncthreads();
  }

  // epilogue: per-row (b) partial sum of exp over this block's 128 cols
#pragma unroll
  for (int i = 0; i < 4; i++) {
#pragma unroll
    for (int r = 0; r < 4; r++) {
      float e = 0.f;
#pragma unroll
      for (int j = 0; j < 4; j++) e += __expf(acc[i][j][r] - NCE_SHIFT);
      e += __shfl_xor(e, 1);
      e += __shfl_xor(e, 2);
      e += __shfl_xor(e, 4);
      e += __shfl_xor(e, 8);
      if (l15 == 0) {
        int b = rowblk * 128 + wm * 64 + i * 16 + quad * 4 + r;
        atomicAdd(&rowsum[(size_t)tw * B_SZ + b], e);
      }
    }
  }
  if (rowblk == colblk && wm == wn) {
#pragma unroll
    for (int i = 0; i < 4; i++)
#pragma unroll
      for (int r = 0; r < 4; r++)
        if (l15 == quad * 4 + r) {
          int b = rowblk * 128 + wm * 64 + i * 16 + quad * 4 + r;
          diagv[(size_t)tw * B_SZ + b] = acc[i][i][r];
        }
  }
}

// ---------------- nce reduction over 65536 rows ----------------
__global__ __launch_bounds__(256) void nce_rows(const float* __restrict__ rowsum,
                                                const float* __restrict__ diagv,
                                                float* __restrict__ parts) {
  int gid = blockIdx.x * 256 + threadIdx.x;  // 16384 threads
  float s = 0.f;
  for (int i = gid; i < 65536; i += 16384)
    s += logf(rowsum[i]) + NCE_SHIFT - diagv[i];  // = -logp_diag
  __shared__ float r[256];
  r[threadIdx.x] = s;
  __syncthreads();
  if (threadIdx.x == 0) {
    float t = 0.f;
    for (int k = 0; k < 256; k++) t += r[k];
    parts[blockIdx.x] = t;
  }
}

__global__ void nce_out(const float* __restrict__ parts, float* __restrict__ out) {
  if (threadIdx.x == 0) {
    float t = 0.f;
    for (int k = 0; k < 64; k++) t += parts[k];
    out[0] = t / 65536.0f;  // B*T*W
  }
}

// ---------------- BN train stats (two stage, fp32) ----------------
__global__ void bn_stage1(const float* __restrict__ h1, float* __restrict__ p1,
                          float* __restrict__ p2) {
  int c = threadIdx.x;  // 128 threads
  int blk = blockIdx.x; // 32 blocks x 128 rows
  float s1 = 0.f, s2 = 0.f;
  for (int r = blk * 128; r < blk * 128 + 128; r++) {
    float v = h1[(size_t)r * 128 + c];
    s1 += v;
    s2 += v * v;
  }
  p1[blk * 128 + c] = s1;
  p2[blk * 128 + c] = s2;
}

__global__ void bn_stage2(const float* __restrict__ p1, const float* __restrict__ p2,
                          const float* __restrict__ g, const float* __restrict__ b,
                          float* __restrict__ sc, float* __restrict__ sh) {
  int c = threadIdx.x;
  float s1 = 0.f, s2 = 0.f;
  for (int k = 0; k < 32; k++) {
    s1 += p1[k * 128 + c];
    s2 += p2[k * 128 + c];
  }
  float mean = s1 * (1.f / 4096.f);
  float var = s2 * (1.f / 4096.f) - mean * mean;  // biased (BN train)
  float scale = g[c] * rsqrtf(var + 1e-5f);
  sc[c] = scale;
  sh[c] = b[c] - mean * scale;
}

// ---------------- BN-apply + ReLU + GEMM2 -> proj (fp32) ----------------
__global__ __launch_bounds__(256) void proj_gemm2(const float* __restrict__ h1,
                                                  const float* __restrict__ sc,
                                                  const float* __restrict__ sh,
                                                  const float* __restrict__ pw2,
                                                  const float* __restrict__ pb2,
                                                  float* __restrict__ out) {
  __shared__ float pw2s[64][129];  // +1 pad breaks bank aliasing
  __shared__ float hs[16][129];
  __shared__ float scs[128], shs[128];
  int tid = threadIdx.x;
  for (int idx = tid; idx < 64 * 128; idx += 256) pw2s[idx >> 7][idx & 127] = pw2[idx];
  if (tid < 128) { scs[tid] = sc[tid]; shs[tid] = sh[tid]; }
  __syncthreads();
  int r0 = blockIdx.x * 64;
  float bb = pb2[tid & 63];
  for (int ch = 0; ch < 4; ch++) {
    int rr0 = r0 + ch * 16;
    for (int idx = tid; idx < 16 * 128; idx += 256) {
      int r = idx >> 7, c = idx & 127;
      float v = h1[(size_t)(rr0 + r) * 128 + c];
      hs[r][c] = fmaxf(v * scs[c] + shs[c], 0.f);
    }
    __syncthreads();
    int oc = tid & 63, og = tid >> 6;
#pragma unroll
    for (int q = 0; q < 4; q++) {
      int row = og * 4 + q;
      float s = bb;
      for (int c = 0; c < 128; c++) s += hs[row][c] * pw2s[oc][c];
      out[(size_t)(rr0 + row) * 64 + oc] = s;
    }
    __syncthreads();
  }
}

extern "C" void kernel_launch(void* const* d_in, const int* in_sizes, int n_in,
                              void* d_out, int out_size, void* d_ws, size_t ws_size,
                              hipStream_t stream) {
  const float* features = (const float*)d_in[0];
  const float* c_t      = (const float*)d_in[1];
  const float* Wk_w     = (const float*)d_in[2];
  const float* Wk_b     = (const float*)d_in[3];
  const float* pw1      = (const float*)d_in[4];
  const float* pb1      = (const float*)d_in[5];
  const float* bn_gamma = (const float*)d_in[6];
  const float* bn_beta  = (const float*)d_in[7];
  const float* pw2      = (const float*)d_in[8];
  const float* pb2      = (const float*)d_in[9];
  const int*   tsp      = (const int*)d_in[10];
  float* out = (float*)d_out;

  // workspace carve-up (~49 MB total)
  char* ws = (char*)d_ws;
  size_t off = 0;
  auto carve = [&](size_t bytes) { void* p = ws + off; off += (bytes + 255) & ~(size_t)255; return p; };
  unsigned short* ct_bf  = (unsigned short*)carve((size_t)4096 * 512 * 2);   // c_t bf16 [bw][h]
  unsigned short* wk_bf  = (unsigned short*)carve((size_t)4096 * 512 * 2);   // Wk bf16 [tc][h]
  unsigned short* pw1_bf = (unsigned short*)carve((size_t)128 * 512 * 2);
  unsigned short* F      = (unsigned short*)carve((size_t)NSLAB * 512 * 256 * 2);
  unsigned short* pred   = (unsigned short*)carve((size_t)16 * 8 * 512 * 256 * 2);
  float* h1     = (float*)carve((size_t)4096 * 128 * 4);
  float* bnp1   = (float*)carve((size_t)32 * 128 * 4);
  float* bnp2   = (float*)carve((size_t)32 * 128 * 4);
  float* bnsc   = (float*)carve((size_t)128 * 4);
  float* bnsh   = (float*)carve((size_t)128 * 4);
  float* parts  = (float*)carve((size_t)2048 * 4);
  float* rowsum = (float*)carve((size_t)65536 * 4);
  float* diagv  = (float*)carve((size_t)65536 * 4);

  cast_bf<<<2048, 256, 0, stream>>>(c_t, ct_bf, 4096 * 512);
  cast_bf<<<2048, 256, 0, stream>>>(Wk_w, wk_bf, 4096 * 512);
  cast_bf<<<64, 256, 0, stream>>>(pw1, pw1_bf, 128 * 512);
  build_slabs2<<<512, 256, 0, stream>>>(features, F, tsp);
  hipMemsetAsync(rowsum, 0, (size_t)65536 * 4, stream);  // atomic accumulator init

  // pred[t][w][a][c] = c_t @ Wk^T + Wk_b   (M=N=4096, K=512)
  gemm_bt<0><<<dim3(32, 32), 256, 0, stream>>>(ct_bf, wk_bf, Wk_b, pred, nullptr, 512);
  // h1 = c_t2d @ pw1^T + pb1   (M=4096, N=128, K=512)
  gemm_bt<1><<<dim3(32, 1), 256, 0, stream>>>(ct_bf, pw1_bf, pb1, nullptr, h1, 512);

  scores_gemm<<<dim3(4, 4, 128), 256, 0, stream>>>(F, pred, tsp, rowsum, diagv);
  nce_rows<<<64, 256, 0, stream>>>(rowsum, diagv, parts);
  nce_out<<<1, 64, 0, stream>>>(parts, out);

  bn_stage1<<<32, 128, 0, stream>>>(h1, bnp1, bnp2);
  bn_stage2<<<1, 128, 0, stream>>>(bnp1, bnp2, bn_gamma, bn_beta, bnsc, bnsh);
  proj_gemm2<<<64, 256, 0, stream>>>(h1, bnsc, bnsh, pw2, pb2, out + 1);
}